// Round 3
// baseline (6064.851 us; speedup 1.0000x reference)
//
#include <hip/hip_runtime.h>

// FixPointLayer: z <- tanh(z @ W^T + x), B=8192, F=1024, 50 steps.
// Round 3: PERSISTENT design exploiting row independence.
//   Each row's iteration chain depends only on itself -> one kernel,
//   256 blocks (1/CU) x 1024 threads (16 waves), 32 rows/block.
//   z: LDS-resident (64 KB, XOR-swizzled) across all iterations.
//   x: f16 registers in C-fragment layout (final step re-reads f32 x).
//   W: f16 (2 MB), streamed from L2 into B-fragments each iteration.
//   Global traffic ~ W + x + out once => L2-stream-bound, no launch/drain
//   latency (round-2 killer), no barriers inside the K-loop.

#define F 1024
#define NSTEPS 49  // GEMM steps after z0 = tanh(x)  (total 50 scan steps)

typedef __attribute__((ext_vector_type(4))) _Float16 f16x4;
typedef __attribute__((ext_vector_type(8))) _Float16 f16x8;
typedef __attribute__((ext_vector_type(4))) float f32x4;

__device__ __forceinline__ float ftanh(float s) {
    // tanh(s) = 1 - 2/(exp(2s)+1); exact at +-inf
    float e = __expf(2.0f * s);
    return 1.0f - __fdividef(2.0f, e + 1.0f);
}

// ---- W fp32 -> f16 ----
__global__ void prep_w(const float* __restrict__ W, _Float16* __restrict__ Wh) {
    int i = blockIdx.x * blockDim.x + threadIdx.x;  // 1024 blk * 256 thr * 4
    float4 wv = ((const float4*)W)[i];
    f16x4 hv = {(_Float16)wv.x, (_Float16)wv.y, (_Float16)wv.z, (_Float16)wv.w};
    ((f16x4*)Wh)[i] = hv;
}

__global__ __launch_bounds__(1024, 4) void fixpoint_persist(
    const float* __restrict__ x, const _Float16* __restrict__ Wh,
    float* __restrict__ out) {
    __shared__ _Float16 zs[32 * F];  // 64 KB, rows XOR-swizzled by ((row&7)<<4)

    const int tid = threadIdx.x;
    const int w   = tid >> 6;   // wave 0..15, owns cols w*64..w*64+63
    const int l   = tid & 63;
    const int lc  = l & 15;
    const int kg  = l >> 4;
    const int r0  = blockIdx.x * 32;

    // ---- z0 = tanh(x) into swizzled LDS ----
    {
        const int row = tid >> 5;          // 0..31
        const int cb  = (tid & 31) * 32;   // 32 cols per thread
        const float* xr = x + (size_t)(r0 + row) * F + cb;
        char* zrow = (char*)zs + row * 2048;
        const int sw = (row & 7) << 4;
#pragma unroll
        for (int q = 0; q < 4; ++q) {
            float4 u0 = ((const float4*)xr)[2 * q];
            float4 u1 = ((const float4*)xr)[2 * q + 1];
            f16x8 v = {(_Float16)ftanh(u0.x), (_Float16)ftanh(u0.y),
                       (_Float16)ftanh(u0.z), (_Float16)ftanh(u0.w),
                       (_Float16)ftanh(u1.x), (_Float16)ftanh(u1.y),
                       (_Float16)ftanh(u1.z), (_Float16)ftanh(u1.w)};
            *(f16x8*)(zrow + (((cb + 8 * q) * 2) ^ sw)) = v;
        }
    }

    // ---- x in C-fragment layout, f16 registers (16 VGPR) ----
    f16x4 xf[2][4];
#pragma unroll
    for (int mf = 0; mf < 2; ++mf)
#pragma unroll
        for (int nf = 0; nf < 4; ++nf)
#pragma unroll
            for (int j = 0; j < 4; ++j)
                xf[mf][nf][j] = (_Float16)x[(size_t)(r0 + mf * 16 + kg * 4 + j) * F
                                            + w * 64 + nf * 16 + lc];
    __syncthreads();

    // per-lane W base: row = output col (w*64 + nf*16 + lc), k-chunk kg*8
    const _Float16* wb = Wh + (size_t)(w * 64 + lc) * F + kg * 8;
    const int swa = (lc & 7) << 4;  // A-read swizzle (rows lc and 16+lc share it)

    for (int it = 0; it < NSTEPS; ++it) {
        f32x4 acc[2][4] = {};
        // ---- K-loop: 32 steps, no barriers; B from global (L2), A from LDS ----
#pragma unroll
        for (int kb = 0; kb < 32; ++kb) {
            f16x8 a0, a1, b[4];
            {
                const int byt = (kb * 64 + kg * 16) ^ swa;
                a0 = *(const f16x8*)((const char*)zs + lc * 2048 + byt);
                a1 = *(const f16x8*)((const char*)zs + (16 + lc) * 2048 + byt);
            }
#pragma unroll
            for (int nf = 0; nf < 4; ++nf)
                b[nf] = *(const f16x8*)(wb + nf * 16 * F + kb * 32);
#pragma unroll
            for (int nf = 0; nf < 4; ++nf) {
                acc[0][nf] = __builtin_amdgcn_mfma_f32_16x16x32_f16(
                    a0, b[nf], acc[0][nf], 0, 0, 0);
                acc[1][nf] = __builtin_amdgcn_mfma_f32_16x16x32_f16(
                    a1, b[nf], acc[1][nf], 0, 0, 0);
            }
        }
        __syncthreads();  // all waves done READING zs
        if (it < NSTEPS - 1) {
            // z = tanh(acc + x) -> back into zs (swizzled, disjoint cols/wave)
#pragma unroll
            for (int mf = 0; mf < 2; ++mf)
#pragma unroll
                for (int nf = 0; nf < 4; ++nf)
#pragma unroll
                    for (int j = 0; j < 4; ++j) {
                        const int lrow = mf * 16 + kg * 4 + j;
                        const int col  = w * 64 + nf * 16 + lc;
                        float zv = ftanh(acc[mf][nf][j] + (float)xf[mf][nf][j]);
                        *(_Float16*)((char*)zs + lrow * 2048 +
                                     ((col * 2) ^ ((lrow & 7) << 4))) = (_Float16)zv;
                    }
        } else {
            // final step: f32 x for extra precision, write fp32 output
#pragma unroll
            for (int mf = 0; mf < 2; ++mf)
#pragma unroll
                for (int nf = 0; nf < 4; ++nf)
#pragma unroll
                    for (int j = 0; j < 4; ++j) {
                        const int gr  = r0 + mf * 16 + kg * 4 + j;
                        const int col = w * 64 + nf * 16 + lc;
                        out[(size_t)gr * F + col] =
                            ftanh(acc[mf][nf][j] + x[(size_t)gr * F + col]);
                    }
        }
        __syncthreads();  // writes visible before next iteration's reads
    }
}

extern "C" void kernel_launch(void* const* d_in, const int* in_sizes, int n_in,
                              void* d_out, int out_size, void* d_ws, size_t ws_size,
                              hipStream_t stream) {
    const float* x = (const float*)d_in[0];   // [8192,1024] fp32
    const float* W = (const float*)d_in[1];   // [1024,1024] fp32
    float* z32 = (float*)d_out;               // final fp32 output
    _Float16* Wh = (_Float16*)d_ws;           // 2 MiB

    prep_w<<<1024, 256, 0, stream>>>(W, Wh);
    fixpoint_persist<<<256, 1024, 0, stream>>>(x, Wh, z32);
}

// Round 4
// 5046.000 us; speedup vs baseline: 1.2019x; 1.2019x over previous
//
#include <hip/hip_runtime.h>
#include <hip/hip_cooperative_groups.h>

namespace cg = cooperative_groups;

// FixPointLayer: z <- tanh(z @ W^T + x), B=8192, F=1024, 50 steps, fp32 out.
// Round 4: ONE cooperative kernel, 256 blocks x 512 thr (1 block/CU).
//   - Row-block independence: block (gm) only needs z rows [gm,gm+256) each
//     iteration -> inter-iteration sync is an 8-block group barrier (atomics,
//     agent-scope fences), not 49 kernel launches.
//   - K-loop: counted vmcnt (never 0 mid-loop), raw s_barrier, A double- +
//     B triple-buffered LDS (112 KB), round-2's proven XOR-swizzle staging.
//   - z f16 ping-pong + x fragment-packed f16 in ws; W f16 L2-resident.

#define F 1024
#define NSTEPS 49  // GEMM steps after z0 = tanh(x) (50 total scan steps)

typedef __attribute__((ext_vector_type(4))) _Float16 f16x4;
typedef __attribute__((ext_vector_type(8))) _Float16 f16x8;
typedef __attribute__((ext_vector_type(4))) float f32x4;

__device__ unsigned g_barctr[32];  // group-barrier counters (zeroed in-kernel)

__device__ __forceinline__ float ftanh(float s) {
    float e = __expf(2.0f * s);
    return 1.0f - __fdividef(2.0f, e + 1.0f);
}

__device__ __forceinline__ void gload_lds16(const void* g, void* l) {
    __builtin_amdgcn_global_load_lds(
        (const __attribute__((address_space(1))) void*)g,
        (__attribute__((address_space(3))) void*)l, 16, 0, 0);
}

// stage A-tile (256x64 of zin) -> abuf : 4 loads/thread
__device__ __forceinline__ void stage_A(const _Float16* __restrict__ zin,
                                        char* abuf, int gm, int kb, int tid) {
    const int lc = tid & 7;
    const int rb = tid >> 3;  // 0..63
#pragma unroll
    for (int r = 0; r < 4; ++r) {
        int row = rb + r * 64;
        int cg = lc ^ (row & 7);  // source pre-XOR; read applies same involution
        gload_lds16(zin + (size_t)(gm + row) * F + kb + cg * 8,
                    abuf + row * 128 + lc * 16);
    }
}
// stage B-tile (128x64 of Wh) -> bbuf : 2 loads/thread
__device__ __forceinline__ void stage_B(const _Float16* __restrict__ Wh,
                                        char* bbuf, int gn, int kb, int tid) {
    const int lc = tid & 7;
    const int rb = tid >> 3;
#pragma unroll
    for (int r = 0; r < 2; ++r) {
        int row = rb + r * 64;
        int cg = lc ^ (row & 7);
        gload_lds16(Wh + (size_t)(gn + row) * F + kb + cg * 8,
                    bbuf + row * 128 + lc * 16);
    }
}

__global__ __launch_bounds__(512, 2) void fixpoint_coop(
    const float* __restrict__ x, const float* __restrict__ W,
    _Float16* __restrict__ Wh, _Float16* __restrict__ zb0,
    _Float16* __restrict__ zb1, _Float16* __restrict__ xfr,
    float* __restrict__ out) {
    cg::grid_group grid = cg::this_grid();
    __shared__ __align__(16) char lds[114688];  // A:2x32K  B:3x16K = 112 KB

    const int tid = threadIdx.x;
    const int bid = blockIdx.x;
    const int w = tid >> 6, l = tid & 63;
    const int wr = w >> 1, wc = w & 1;          // 4x2 wave grid, 64x64 each
    const int kg = l >> 4, lc16 = l & 15;
    // group peers (same mt) likely share an XCD (perf heuristic only)
    const int mt = (bid & 7) * 4 + (bid >> 6);  // 0..31
    const int nt = (bid >> 3) & 7;              // 0..7
    const int gm = mt * 256, gn = nt * 128;

    // ---- init: Wh slice, z0 = tanh(x) slice, x fragments, barrier ctr ----
    {
        size_t o = ((size_t)bid * 512 + tid) * 8;  // covers all of W once
        float4 a = ((const float4*)(W + o))[0];
        float4 b = ((const float4*)(W + o))[1];
        f16x8 wv = {(_Float16)a.x, (_Float16)a.y, (_Float16)a.z, (_Float16)a.w,
                    (_Float16)b.x, (_Float16)b.y, (_Float16)b.z, (_Float16)b.w};
        *(f16x8*)(Wh + o) = wv;
    }
    {
        size_t ro = (size_t)(bid * 32 + (tid >> 4)) * F + (tid & 15) * 64;
        const float* xr = x + ro;
        _Float16* zr = zb0 + ro;
#pragma unroll
        for (int q = 0; q < 8; ++q) {
            float4 a = ((const float4*)xr)[2 * q];
            float4 b = ((const float4*)xr)[2 * q + 1];
            f16x8 v = {(_Float16)ftanh(a.x), (_Float16)ftanh(a.y),
                       (_Float16)ftanh(a.z), (_Float16)ftanh(a.w),
                       (_Float16)ftanh(b.x), (_Float16)ftanh(b.y),
                       (_Float16)ftanh(b.z), (_Float16)ftanh(b.w)};
            *(f16x8*)(zr + 8 * q) = v;
        }
    }
    {
        _Float16* xd = xfr + ((size_t)bid * 512 + tid) * 64;
#pragma unroll
        for (int m = 0; m < 4; ++m)
#pragma unroll
            for (int n = 0; n < 4; ++n) {
                f16x4 v;
#pragma unroll
                for (int j = 0; j < 4; ++j)
                    v[j] = (_Float16)x[(size_t)(gm + wr * 64 + m * 16 + kg * 4 + j) * F
                                       + gn + wc * 64 + n * 16 + lc16];
                *(f16x4*)(xd + (m * 4 + n) * 4) = v;
            }
    }
    if (tid == 0 && nt == 0) g_barctr[mt] = 0;
    grid.sync();  // Wh, z0, xfr, counters visible grid-wide

    char* const ab[2] = {lds, lds + 32768};
    char* const bb[3] = {lds + 65536, lds + 81920, lds + 98304};

    for (int it = 0; it < NSTEPS; ++it) {
        const _Float16* zin = (it & 1) ? zb1 : zb0;
        _Float16* zout = (it & 1) ? zb0 : zb1;

        // prologue: A0,B0,A1,B1 -> 12 outstanding
        stage_A(zin, ab[0], gm, 0, tid);
        stage_B(Wh, bb[0], gn, 0, tid);
        stage_A(zin, ab[1], gm, 64, tid);
        stage_B(Wh, bb[1], gn, 64, tid);

        f32x4 acc[4][4];
#pragma unroll
        for (int m = 0; m < 4; ++m)
#pragma unroll
            for (int n = 0; n < 4; ++n) acc[m][n] = (f32x4){0.f, 0.f, 0.f, 0.f};

#pragma unroll
        for (int t = 0; t < 16; ++t) {
            // counted waits: A(t),B(t) complete; newer prefetches stay in flight
            if (t == 0)       asm volatile("s_waitcnt vmcnt(6)" ::: "memory");
            else if (t == 15) asm volatile("s_waitcnt vmcnt(0)" ::: "memory");
            else              asm volatile("s_waitcnt vmcnt(2)" ::: "memory");
            __builtin_amdgcn_s_barrier();
            asm volatile("" ::: "memory");  // no LDS reads hoist above barrier
            if (t >= 1 && t <= 14) stage_A(zin, ab[(t + 1) & 1], gm, (t + 1) * 64, tid);
            if (t <= 13)           stage_B(Wh, bb[(t + 2) % 3], gn, (t + 2) * 64, tid);

            const char* A = ab[t & 1];
            const char* B = bb[t % 3];
            f16x8 af[2][4], bf[2][4];
#pragma unroll
            for (int kh = 0; kh < 2; ++kh) {
                const int sw = (((kh * 4 + kg) ^ (lc16 & 7)) << 4);
#pragma unroll
                for (int m = 0; m < 4; ++m)
                    af[kh][m] = *(const f16x8*)(A + (wr * 64 + m * 16 + lc16) * 128 + sw);
#pragma unroll
                for (int n = 0; n < 4; ++n)
                    bf[kh][n] = *(const f16x8*)(B + (wc * 64 + n * 16 + lc16) * 128 + sw);
            }
            __builtin_amdgcn_s_setprio(1);
#pragma unroll
            for (int kh = 0; kh < 2; ++kh)
#pragma unroll
                for (int m = 0; m < 4; ++m)
#pragma unroll
                    for (int n = 0; n < 4; ++n)
                        acc[m][n] = __builtin_amdgcn_mfma_f32_16x16x32_f16(
                            af[kh][m], bf[kh][n], acc[m][n], 0, 0, 0);
            __builtin_amdgcn_s_setprio(0);
        }

        // ---- epilogue ----
        const bool lastit = (it == NSTEPS - 1);
        _Float16 xloc[64];
        if (!lastit) {
            const f16x8* xs = (const f16x8*)(xfr + ((size_t)bid * 512 + tid) * 64);
#pragma unroll
            for (int q = 0; q < 8; ++q) *(f16x8*)(xloc + 8 * q) = xs[q];
        }
#pragma unroll
        for (int m = 0; m < 4; ++m)
#pragma unroll
            for (int j = 0; j < 4; ++j) {
                const size_t gr = gm + wr * 64 + m * 16 + kg * 4 + j;
#pragma unroll
                for (int n = 0; n < 4; ++n) {
                    const int gc = gn + wc * 64 + n * 16 + lc16;
                    if (lastit) {
                        out[gr * F + gc] = ftanh(acc[m][n][j] + x[gr * F + gc]);
                    } else {
                        zout[gr * F + gc] =
                            (_Float16)ftanh(acc[m][n][j] + (float)xloc[(m * 4 + n) * 4 + j]);
                    }
                }
            }

        if (!lastit) {
            // 8-block group barrier (blocks sharing mt), agent-scope
            __threadfence();
            __syncthreads();
            if (tid == 0) {
                __hip_atomic_fetch_add(&g_barctr[mt], 1u, __ATOMIC_RELEASE,
                                       __HIP_MEMORY_SCOPE_AGENT);
                const unsigned tgt = 8u * (unsigned)(it + 1);
                while (__hip_atomic_load(&g_barctr[mt], __ATOMIC_ACQUIRE,
                                         __HIP_MEMORY_SCOPE_AGENT) < tgt) {}
            }
            __syncthreads();
        }
    }
}

extern "C" void kernel_launch(void* const* d_in, const int* in_sizes, int n_in,
                              void* d_out, int out_size, void* d_ws, size_t ws_size,
                              hipStream_t stream) {
    const float* x = (const float*)d_in[0];   // [8192,1024] fp32
    const float* W = (const float*)d_in[1];   // [1024,1024] fp32
    float* out = (float*)d_out;               // final fp32 output
    char* ws = (char*)d_ws;
    _Float16* zb0 = (_Float16*)ws;                   // 16 MiB
    _Float16* zb1 = (_Float16*)(ws + (16u << 20));   // 16 MiB
    _Float16* Wh  = (_Float16*)(ws + (32u << 20));   // 2 MiB
    _Float16* xfr = (_Float16*)(ws + (34u << 20));   // 16 MiB (ends at 50 MiB)

    void* args[] = {(void*)&x, (void*)&W, (void*)&Wh, (void*)&zb0,
                    (void*)&zb1, (void*)&xfr, (void*)&out};
    hipLaunchCooperativeKernel((const void*)fixpoint_coop, dim3(256), dim3(512),
                               args, 0, stream);
}

// Round 5
// 1189.720 us; speedup vs baseline: 5.0977x; 4.2413x over previous
//
#include <hip/hip_runtime.h>

// FixPointLayer: z <- tanh(z @ W^T + x), B=8192, F=1024, 50 steps, fp32 out.
// Round 5: back to the proven multi-launch ping-pong (round 2 skeleton =
// best so far), with three targeted fixes:
//   1. XCD mt-grouping block swizzle: the 8 blocks sharing an A(z)-panel land
//      on one XCD -> z fetched once per XCD (round 2 refetched z per-XCD).
//   2. 512-thr blocks (8 waves) x 64KB dbuf LDS -> 2 blocks/CU = 16 waves/CU.
//   3. Counted-vmcnt 1-deep prefetch pipeline (T3-min): one raw s_barrier per
//      K-step; vmcnt(0) waits only loads issued a full step earlier; setprio
//      around MFMA cluster. x pre-packed in C-fragment order (vector reads).

#define F 1024
#define NITER 50

typedef __attribute__((ext_vector_type(4))) _Float16 f16x4;
typedef __attribute__((ext_vector_type(8))) _Float16 f16x8;
typedef __attribute__((ext_vector_type(4))) float f32x4;

__device__ __forceinline__ float ftanh(float s) {
    float e = __expf(2.0f * s);
    return 1.0f - __fdividef(2.0f, e + 1.0f);
}

__device__ __forceinline__ void gload_lds16(const void* g, void* l) {
    __builtin_amdgcn_global_load_lds(
        (const __attribute__((address_space(1))) void*)g,
        (__attribute__((address_space(3))) void*)l, 16, 0, 0);
}

// ---- W fp32 -> f16 ----
__global__ void prep_w(const float* __restrict__ W, _Float16* __restrict__ Wh) {
    int i = blockIdx.x * blockDim.x + threadIdx.x;
    float4 wv = ((const float4*)W)[i];
    f16x4 hv = {(_Float16)wv.x, (_Float16)wv.y, (_Float16)wv.z, (_Float16)wv.w};
    ((f16x4*)Wh)[i] = hv;
}

// ---- z0 = tanh(x) -> f16 ----
__global__ void prep_z0(const float* __restrict__ x, _Float16* __restrict__ zb0) {
    int i = blockIdx.x * blockDim.x + threadIdx.x;
    float4 xv = ((const float4*)x)[i];
    f16x4 zv = {(_Float16)ftanh(xv.x), (_Float16)ftanh(xv.y),
                (_Float16)ftanh(xv.z), (_Float16)ftanh(xv.w)};
    ((f16x4*)zb0)[i] = zv;
}

// ---- pack x into per-(tile,thread) C-fragment order, f16 ----
// layout: xfr[ ((mt*8+nt)*512 + tid)*32 + (m*2+n)*4 + j ]
__global__ void prep_xfr(const float* __restrict__ x, _Float16* __restrict__ xfr) {
    const int bid = blockIdx.x;        // 512: mt = bid>>3, nt = bid&7
    const int tid = threadIdx.x;       // 512
    const int mt = bid >> 3, nt = bid & 7;
    const int w = tid >> 6, l = tid & 63;
    const int wr = w >> 2, wc = w & 3;
    const int kg = l >> 4, lc16 = l & 15;
    const int gm = mt * 128, gn = nt * 128;
    _Float16* dst = xfr + (((size_t)(mt * 8 + nt) * 512 + tid) << 5);
#pragma unroll
    for (int m = 0; m < 4; ++m)
#pragma unroll
        for (int n = 0; n < 2; ++n) {
            f16x4 v;
#pragma unroll
            for (int j = 0; j < 4; ++j)
                v[j] = (_Float16)x[(size_t)(gm + wr * 64 + m * 16 + kg * 4 + j) * F
                                   + gn + wc * 32 + n * 16 + lc16];
            *(f16x4*)(dst + (m * 2 + n) * 4) = v;
        }
}

// stage a 128x64 f16 tile (rows src[row0+r], cols kb..kb+63) into dst LDS.
// 512 threads x 2 loads x 16B; XOR-preswizzled source, linear LDS dest.
__device__ __forceinline__ void stage_tile(const _Float16* __restrict__ src,
                                           char* dst, int row0, int kb, int tid) {
    const int lc = tid & 7;
    const int rb = tid >> 3;  // 0..63
#pragma unroll
    for (int r = 0; r < 2; ++r) {
        int row = rb + r * 64;
        int cg = lc ^ (row & 7);
        gload_lds16(src + (size_t)(row0 + row) * F + kb + cg * 8,
                    dst + row * 128 + lc * 16);
    }
}

__global__ __launch_bounds__(512, 4) void fixpoint_gemm(
    const _Float16* __restrict__ zin, _Float16* __restrict__ zout,
    const _Float16* __restrict__ Wh, const _Float16* __restrict__ xfr,
    const float* __restrict__ x32, float* __restrict__ out) {

    __shared__ __align__(16) char lds[65536];
    char* const ab[2] = {lds, lds + 16384};
    char* const bb[2] = {lds + 32768, lds + 49152};

    const int tid = threadIdx.x;
    const int w = tid >> 6, l = tid & 63;
    const int wr = w >> 2, wc = w & 3;   // 2M x 4N wave grid; wave tile 64x32
    const int kg = l >> 4, lc16 = l & 15;
    // XCD mt-grouping swizzle: XCD = bid%8 (hw round-robin). Blocks with the
    // same mt (sharing the z A-panel) get the same (xcd, q&7) -> one XCD.
    const int bid = blockIdx.x;
    const int xcd = bid & 7, q = bid >> 3;
    const int mt = xcd * 8 + (q & 7);    // 0..63
    const int nt = q >> 3;               // 0..7
    const int gm = mt * 128, gn = nt * 128;

    // prologue: stage K-tile 0
    stage_tile(zin, ab[0], gm, 0, tid);
    stage_tile(Wh, bb[0], gn, 0, tid);

    f32x4 acc[4][2];
#pragma unroll
    for (int m = 0; m < 4; ++m)
#pragma unroll
        for (int n = 0; n < 2; ++n) acc[m][n] = (f32x4){0.f, 0.f, 0.f, 0.f};

    int cur = 0;
#pragma unroll
    for (int kt = 0; kt < 16; ++kt) {
        // my tile-kt loads (issued a full step ago, except kt=0) done:
        asm volatile("s_waitcnt vmcnt(0)" ::: "memory");
        __builtin_amdgcn_s_barrier();       // all waves' tile-kt loads landed;
        asm volatile("" ::: "memory");      // no LDS reads hoist above barrier
        // 1-deep prefetch into the buffer freed by the barrier (tile kt-1's)
        if (kt < 15) {
            stage_tile(zin, ab[cur ^ 1], gm, (kt + 1) * 64, tid);
            stage_tile(Wh, bb[cur ^ 1], gn, (kt + 1) * 64, tid);
        }
        const char* A = ab[cur];
        const char* B = bb[cur];
        f16x8 af[2][4], bf[2][2];
#pragma unroll
        for (int kh = 0; kh < 2; ++kh) {
            const int sw = ((kh * 4 + kg) ^ (lc16 & 7)) << 4;
#pragma unroll
            for (int m = 0; m < 4; ++m)
                af[kh][m] = *(const f16x8*)(A + (wr * 64 + m * 16 + lc16) * 128 + sw);
#pragma unroll
            for (int n = 0; n < 2; ++n)
                bf[kh][n] = *(const f16x8*)(B + (wc * 32 + n * 16 + lc16) * 128 + sw);
        }
        __builtin_amdgcn_s_setprio(1);
#pragma unroll
        for (int kh = 0; kh < 2; ++kh)
#pragma unroll
            for (int m = 0; m < 4; ++m)
#pragma unroll
                for (int n = 0; n < 2; ++n)
                    acc[m][n] = __builtin_amdgcn_mfma_f32_16x16x32_f16(
                        af[kh][m], bf[kh][n], acc[m][n], 0, 0, 0);
        __builtin_amdgcn_s_setprio(0);
        cur ^= 1;
    }

    // ---- epilogue ----
    const bool lastit = (out != nullptr);
    if (!lastit) {
        _Float16 xl[32];
        {
            const f16x8* xp =
                (const f16x8*)(xfr + (((size_t)(mt * 8 + nt) * 512 + tid) << 5));
#pragma unroll
            for (int qq = 0; qq < 4; ++qq) *(f16x8*)(xl + 8 * qq) = xp[qq];
        }
#pragma unroll
        for (int m = 0; m < 4; ++m)
#pragma unroll
            for (int j = 0; j < 4; ++j) {
                const size_t gr = gm + wr * 64 + m * 16 + kg * 4 + j;
#pragma unroll
                for (int n = 0; n < 2; ++n) {
                    const int gc = gn + wc * 32 + n * 16 + lc16;
                    zout[gr * F + gc] =
                        (_Float16)ftanh(acc[m][n][j] + (float)xl[(m * 2 + n) * 4 + j]);
                }
            }
    } else {
#pragma unroll
        for (int m = 0; m < 4; ++m)
#pragma unroll
            for (int j = 0; j < 4; ++j) {
                const size_t gr = gm + wr * 64 + m * 16 + kg * 4 + j;
#pragma unroll
                for (int n = 0; n < 2; ++n) {
                    const int gc = gn + wc * 32 + n * 16 + lc16;
                    out[gr * F + gc] = ftanh(acc[m][n][j] + x32[gr * F + gc]);
                }
            }
    }
}

extern "C" void kernel_launch(void* const* d_in, const int* in_sizes, int n_in,
                              void* d_out, int out_size, void* d_ws, size_t ws_size,
                              hipStream_t stream) {
    const float* x = (const float*)d_in[0];   // [8192,1024] fp32
    const float* W = (const float*)d_in[1];   // [1024,1024] fp32
    float* out = (float*)d_out;               // final fp32 output
    char* ws = (char*)d_ws;
    _Float16* zb0 = (_Float16*)ws;                   // 16 MiB
    _Float16* zb1 = (_Float16*)(ws + (16u << 20));   // 16 MiB
    _Float16* Wh  = (_Float16*)(ws + (32u << 20));   // 2 MiB
    _Float16* xfr = (_Float16*)(ws + (34u << 20));   // 16 MiB (total 50 MiB)

    prep_w<<<1024, 256, 0, stream>>>(W, Wh);
    prep_z0<<<8192, 256, 0, stream>>>(x, zb0);
    prep_xfr<<<512, 512, 0, stream>>>(x, xfr);
    for (int it = 1; it < NITER; ++it) {
        _Float16* zin  = (it & 1) ? zb0 : zb1;
        _Float16* zout = (it & 1) ? zb1 : zb0;
        bool last = (it == NITER - 1);
        fixpoint_gemm<<<512, 512, 0, stream>>>(zin, zout, Wh, xfr, x,
                                               last ? out : nullptr);
    }
}